// Round 14
// baseline (315.257 us; speedup 1.0000x reference)
//
#include <hip/hip_runtime.h>
#include <hip/hip_bf16.h>

// CrossModalMDTA on gfx950 — round 14.
// Dispatch-overlap: proj split into proj_qk and proj_v; proj_v blocks merged
// INTO the dwgram dispatch (independent work: dwgram needs only q/k from
// proj_qk; proj_v writes kv0 v-half read only by final). gemm_body refactored
// to take a shared-mem pointer so both paths share one LDS union buffer.

typedef __attribute__((ext_vector_type(8))) short short8;   // 8 x bf16
typedef __attribute__((ext_vector_type(4))) float f32x4;    // MFMA accum

static __device__ __forceinline__ float b2f(unsigned short u) {
    return __uint_as_float(((unsigned)u) << 16);
}
static __device__ __forceinline__ unsigned short f2b(float f) {
    unsigned u = __float_as_uint(f);
    u += 0x7FFFu + ((u >> 16) & 1u);          // RNE
    return (unsigned short)(u >> 16);
}
static __device__ __forceinline__ unsigned short f2bh(float f) {
    union { __hip_bfloat16 h; unsigned short u; } cv;
    cv.h = __float2bfloat16(f);
    return cv.u;
}

// one launch converts both weight tensors
__global__ void cvt_weights(const float* __restrict__ w_q,
                            const float* __restrict__ w_kv,
                            unsigned short* __restrict__ wq_b,
                            unsigned short* __restrict__ wkv_b) {
    const int i = blockIdx.x * 256 + threadIdx.x;
    if (i < 192 * 192) wq_b[i] = f2b(w_q[i]);
    const int j = i - 192 * 192;
    if (j >= 0 && j < 384 * 192) wkv_b[j] = f2b(w_kv[j]);
}

// ---------------------------------------------------------------------------
// GEMM body (r8-proven): C[m,n] = sum_k A[m,k]*B[k,n], K=192,
// tile 192m x 128n, 4 waves, split-K=64 double-buffered. Shared mem passed in
// (needs 2*128*72 ushorts = 36864 B).
// ---------------------------------------------------------------------------
template<typename Bty, typename Oty>
static __device__ __forceinline__ void gemm_body(
    const unsigned short* __restrict__ A,   // bf16 [192 x 192]
    const Bty* __restrict__ B,              // [192 x N] fp32 or bf16
    Oty* __restrict__ C,                    // [192 x N] bf16(ushort) or fp32
    long n0, void* smem_raw)
{
    constexpr long N = 16384;
    constexpr int K = 192;
    auto Bs = reinterpret_cast<unsigned short (*)[128][72]>(smem_raw); // [2][..]
    const int tid  = threadIdx.x;
    const int wave = tid >> 6;
    const int lane = tid & 63;
    const int l15  = lane & 15;
    const int g    = lane >> 4;

    const int nc = tid & 127;
    const int kb = tid >> 7;

    float fv[4][8];
    unsigned short sv[4][8];

    auto load_regs = [&](int s) {
#pragma unroll
        for (int i = 0; i < 4; ++i) {
            const int kc = kb + 2 * i;
            const Bty* bp = B + (long)(s * 64 + kc * 8) * N + n0 + nc;
#pragma unroll
            for (int j = 0; j < 8; ++j) {
                if constexpr (sizeof(Bty) == 4) fv[i][j] = (float)bp[j * N];
                else                            sv[i][j] = bp[j * N];
            }
        }
    };
    auto write_lds = [&](int buf) {
#pragma unroll
        for (int i = 0; i < 4; ++i) {
            const int kc = kb + 2 * i;
            unsigned w[4];
#pragma unroll
            for (int t = 0; t < 4; ++t) {
                if constexpr (sizeof(Bty) == 4)
                    w[t] = (unsigned)f2bh(fv[i][2*t]) | ((unsigned)f2bh(fv[i][2*t+1]) << 16);
                else
                    w[t] = (unsigned)sv[i][2*t] | ((unsigned)sv[i][2*t+1] << 16);
            }
            uint4 pk = {w[0], w[1], w[2], w[3]};
            *reinterpret_cast<uint4*>(&Bs[buf][nc][kc * 8]) = pk;
        }
    };

    f32x4 acc[3][8];
#pragma unroll
    for (int i = 0; i < 3; ++i)
#pragma unroll
        for (int j = 0; j < 8; ++j) acc[i][j] = {0.f, 0.f, 0.f, 0.f};

    load_regs(0);
    write_lds(0);
    __syncthreads();

#pragma unroll
    for (int s = 0; s < 3; ++s) {
        const int buf = s & 1;
        if (s < 2) load_regs(s + 1);
#pragma unroll
        for (int s32 = 0; s32 < 2; ++s32) {
            short8 af[3];
#pragma unroll
            for (int mt = 0; mt < 3; ++mt)
                af[mt] = *reinterpret_cast<const short8*>(
                    A + (long)(wave * 48 + mt * 16 + l15) * K + s * 64 + s32 * 32 + g * 8);
            short8 bf[8];
#pragma unroll
            for (int nt = 0; nt < 8; ++nt)
                bf[nt] = *reinterpret_cast<const short8*>(
                    &Bs[buf][nt * 16 + l15][s32 * 32 + g * 8]);
#pragma unroll
            for (int nt = 0; nt < 8; ++nt)
#pragma unroll
                for (int mt = 0; mt < 3; ++mt)
                    acc[mt][nt] = __builtin_amdgcn_mfma_f32_16x16x32_bf16(
                        af[mt], bf[nt], acc[mt][nt], 0, 0, 0);
        }
        if (s < 2) {
            write_lds(buf ^ 1);
            __syncthreads();
        }
    }

#pragma unroll
    for (int mt = 0; mt < 3; ++mt) {
#pragma unroll
        for (int nt = 0; nt < 8; ++nt) {
            const int row = wave * 48 + mt * 16 + g * 4;
            const long col = n0 + nt * 16 + l15;
#pragma unroll
            for (int r = 0; r < 4; ++r) {
                const float v = acc[mt][nt][r];
                if constexpr (sizeof(Oty) == 4)
                    C[(long)(row + r) * N + col] = v;
                else
                    C[(long)(row + r) * N + col] = f2b(v);
            }
        }
    }
}

// q + k projection only: y==0 -> q0 ; y==1 -> kv0 k-half
__global__ void __launch_bounds__(256) proj_qk(
    const unsigned short* __restrict__ wq_b,
    const unsigned short* __restrict__ wkv_b,
    const float* __restrict__ f_opt,
    const float* __restrict__ f_sar,
    unsigned short* __restrict__ q0,
    unsigned short* __restrict__ kv0)
{
    constexpr long N = 16384;
    __shared__ __align__(16) unsigned char smem[2 * 128 * 72 * 2];
    const int b = blockIdx.z;
    const long n0 = (long)blockIdx.x * 128;
    if (blockIdx.y == 0) {
        gemm_body<float, unsigned short>(
            wq_b, f_opt + (long)b * 192 * N, q0 + (long)b * 192 * N, n0, smem);
    } else {
        gemm_body<float, unsigned short>(
            wkv_b, f_sar + (long)b * 192 * N,
            kv0 + (long)b * 384 * N, n0, smem);
    }
}

// ---------------------------------------------------------------------------
// Merged dispatch: x < 64 -> dwgram block (chunk = x&15, h = x>>4);
// x >= 64 -> proj_v block (n-tile x-64). Independent work, shared launch.
// LDS union: 52224 B (dwgram needs [2][96][136] ushorts).
// ---------------------------------------------------------------------------
__global__ void __launch_bounds__(256) dwgram_projv(
    const unsigned short* __restrict__ q0,   // [B][192][N] bf16
    const unsigned short* __restrict__ kv0,  // [B][384][N] bf16
    const unsigned short* __restrict__ wkv_b,// [384][192] bf16
    const float* __restrict__ f_sar,
    const float* __restrict__ w_qdw,         // [192][9]
    const float* __restrict__ w_kvdw,        // [384][9]
    float* __restrict__ Gpart,               // [B][4][16][2304]
    float* __restrict__ nqPart,              // [B][192][16]
    float* __restrict__ nkPart,              // [B][192][16]
    unsigned short* __restrict__ kv0_out)    // same as kv0 (v-half written)
{
    constexpr long NP = 16384;
    __shared__ __align__(16) unsigned char smem_u[2 * 96 * 136 * 2]; // 52224 B
    const int b = blockIdx.z;

    if (blockIdx.x >= 64) {
        // ---- proj_v: kv0 v-half = Wkv[192:384] * f_sar
        const long n0 = (long)(blockIdx.x - 64) * 128;
        gemm_body<float, unsigned short>(
            wkv_b + (size_t)192 * 192, f_sar + (long)b * 192 * NP,
            kv0_out + ((long)b * 384 + 192) * NP, n0, smem_u);
        return;
    }

    // ---- dwgram (round-10 body)
    const int chunk = blockIdx.x & 15;
    const int h     = blockIdx.x >> 4;

    const int tid  = threadIdx.x;
    const int wave = tid >> 6;               // 0..3 = k-step
    const int lane = tid & 63;
    const int l15  = lane & 15;
    const int g    = lane >> 4;

    const int w0     = (tid & 15) * 8;
    const int chBase = tid >> 4;             // 0..15

    auto sm = reinterpret_cast<unsigned short (*)[96][136]>(smem_u); // [2][..]

    const unsigned short* srcs[6];
    float wt[6][9];
    float nacc[6];
#pragma unroll
    for (int tt = 0; tt < 6; ++tt) {
        const int ch_loc = tt * 16 + chBase;
        const float* wp;
        if (ch_loc < 48) {
            const int c = 48 * h + ch_loc;
            srcs[tt] = q0 + ((long)b * 192 + c) * NP;
            wp = w_qdw + c * 9;
        } else {
            const int c = 48 * h + ch_loc - 48;
            srcs[tt] = kv0 + ((long)b * 384 + c) * NP;
            wp = w_kvdw + c * 9;
        }
#pragma unroll
        for (int i = 0; i < 9; ++i) wt[tt][i] = wp[i];
        nacc[tt] = 0.f;
    }

    f32x4 acc[3][3];
#pragma unroll
    for (int i = 0; i < 3; ++i)
#pragma unroll
        for (int j = 0; j < 3; ++j) acc[i][j] = {0.f, 0.f, 0.f, 0.f};

    auto dw_step = [&](int s, int buf) {
        const int r = chunk * 8 + s;
#pragma unroll
        for (int tt = 0; tt < 6; ++tt) {
            float a8[8] = {0, 0, 0, 0, 0, 0, 0, 0};
#pragma unroll
            for (int dy = 0; dy < 3; ++dy) {
                const int hy = r + dy - 1;
                if (hy < 0 || hy > 127) continue;
                const unsigned short* row = srcs[tt] + hy * 128 + w0;
                float rr[10];
                const short8 v = *reinterpret_cast<const short8*>(row);
#pragma unroll
                for (int i = 0; i < 8; ++i) rr[i + 1] = b2f((unsigned short)v[i]);
                const float left  = __shfl_up(rr[8], 1);
                const float right = __shfl_down(rr[1], 1);
                rr[0] = (l15 > 0)  ? left  : 0.f;
                rr[9] = (l15 < 15) ? right : 0.f;
#pragma unroll
                for (int j = 0; j < 8; ++j)
                    a8[j] += wt[tt][dy*3+0]*rr[j] + wt[tt][dy*3+1]*rr[j+1]
                           + wt[tt][dy*3+2]*rr[j+2];
            }
            float ss = 0.f;
#pragma unroll
            for (int j = 0; j < 8; ++j) ss += a8[j] * a8[j];
            nacc[tt] += ss;
            unsigned u[4];
#pragma unroll
            for (int t2 = 0; t2 < 4; ++t2)
                u[t2] = (unsigned)f2bh(a8[2*t2]) | ((unsigned)f2bh(a8[2*t2+1]) << 16);
            uint4 pk = {u[0], u[1], u[2], u[3]};
            *reinterpret_cast<uint4*>(&sm[buf][tt * 16 + chBase][w0]) = pk;
        }
    };

    auto mma_step = [&](int buf) {
        short8 af[3], bf[3];
#pragma unroll
        for (int mt = 0; mt < 3; ++mt)
            af[mt] = *reinterpret_cast<const short8*>(
                &sm[buf][mt * 16 + l15][wave * 32 + g * 8]);
#pragma unroll
        for (int nt = 0; nt < 3; ++nt)
            bf[nt] = *reinterpret_cast<const short8*>(
                &sm[buf][48 + nt * 16 + l15][wave * 32 + g * 8]);
#pragma unroll
        for (int mt = 0; mt < 3; ++mt)
#pragma unroll
            for (int nt = 0; nt < 3; ++nt)
                acc[mt][nt] = __builtin_amdgcn_mfma_f32_16x16x32_bf16(
                    af[mt], bf[nt], acc[mt][nt], 0, 0, 0);
    };

    dw_step(0, 0);
    __syncthreads();
#pragma unroll 1
    for (int s = 0; s < 8; ++s) {
        const int buf = s & 1;
        if (s < 7) dw_step(s + 1, buf ^ 1);
        mma_step(buf);
        __syncthreads();
    }

    float* Gt = reinterpret_cast<float*>(smem_u);
#pragma unroll
    for (int mt = 0; mt < 3; ++mt)
#pragma unroll
        for (int nt = 0; nt < 3; ++nt)
#pragma unroll
            for (int r = 0; r < 4; ++r)
                Gt[wave * 2304 + (mt*16 + g*4 + r) * 48 + nt*16 + l15] = acc[mt][nt][r];
    __syncthreads();

    float* gout = Gpart + (((long)(b * 4 + h)) * 16 + chunk) * 2304;
    for (int i = tid; i < 2304; i += 256)
        gout[i] = Gt[i] + Gt[2304 + i] + Gt[4608 + i] + Gt[6912 + i];

#pragma unroll
    for (int tt = 0; tt < 6; ++tt) {
        float ssv = nacc[tt];
        ssv += __shfl_xor(ssv, 1);
        ssv += __shfl_xor(ssv, 2);
        ssv += __shfl_xor(ssv, 4);
        ssv += __shfl_xor(ssv, 8);
        if ((tid & 15) == 0) {
            const int ch_loc = tt * 16 + chBase;
            if (ch_loc < 48)
                nqPart[((long)b * 192 + 48 * h + ch_loc) * 16 + chunk] = ssv;
            else
                nkPart[((long)b * 192 + 48 * h + ch_loc - 48) * 16 + chunk] = ssv;
        }
    }
}

// ---------------------------------------------------------------------------
// final GEMM fused with dw3x3(v): block = (image row r, batch b). (round 13)
// ---------------------------------------------------------------------------
__global__ void __launch_bounds__(256) final_gemm_fused(
    const unsigned short* __restrict__ Mmat,   // [B,192,192] bf16
    const unsigned short* __restrict__ kv0,    // [B,384,N] (v = ch 192..383)
    const float* __restrict__ w_kvdw,          // [384][9]
    float* __restrict__ out)                   // [B,192,N] fp32
{
    constexpr long N = 16384;
    constexpr int K = 192;
    const int r = blockIdx.x;                  // image row 0..127
    const int b = blockIdx.z;
    const unsigned short* v0 = kv0 + ((long)b * 384 + 192) * N;
    const unsigned short* A  = Mmat + (long)b * 192 * 192;
    float* C = out + (long)b * 192 * N;

    const int tid  = threadIdx.x;
    const int wave = tid >> 6;
    const int lane = tid & 63;
    const int l15  = lane & 15;
    const int g    = lane >> 4;

    __shared__ __align__(16) unsigned short Bsv[128][200];   // [px][ch] 51.2 KB

    const int l16   = tid & 15;
    const int pBase = l16 * 8;
    const int cp    = tid >> 4;                // 0..15

#pragma unroll
    for (int t6 = 0; t6 < 6; ++t6) {
        const int c0 = t6 * 32 + cp * 2;
        float a8[2][8];
#pragma unroll
        for (int e = 0; e < 2; ++e)
#pragma unroll
            for (int j = 0; j < 8; ++j) a8[e][j] = 0.f;

#pragma unroll
        for (int e = 0; e < 2; ++e) {
            const int c = c0 + e;
            const float* wp = w_kvdw + (192 + c) * 9;
            float wt[9];
#pragma unroll
            for (int i = 0; i < 9; ++i) wt[i] = wp[i];
            const unsigned short* src = v0 + (long)c * N;
#pragma unroll
            for (int dy = 0; dy < 3; ++dy) {
                const int hy = r + dy - 1;
                if (hy < 0 || hy > 127) continue;
                const unsigned short* row = src + hy * 128 + pBase;
                float rr[10];
                const short8 v = *reinterpret_cast<const short8*>(row);
#pragma unroll
                for (int i = 0; i < 8; ++i) rr[i + 1] = b2f((unsigned short)v[i]);
                const float left  = __shfl_up(rr[8], 1);
                const float right = __shfl_down(rr[1], 1);
                rr[0] = (l16 > 0)  ? left  : 0.f;
                rr[9] = (l16 < 15) ? right : 0.f;
#pragma unroll
                for (int j = 0; j < 8; ++j)
                    a8[e][j] += wt[dy*3+0]*rr[j] + wt[dy*3+1]*rr[j+1]
                              + wt[dy*3+2]*rr[j+2];
            }
        }
#pragma unroll
        for (int j = 0; j < 8; ++j) {
            const unsigned u = (unsigned)f2bh(a8[0][j])
                             | ((unsigned)f2bh(a8[1][j]) << 16);
            *reinterpret_cast<unsigned*>(&Bsv[pBase + j][c0]) = u;
        }
    }
    __syncthreads();

    f32x4 acc[3][8];
#pragma unroll
    for (int i = 0; i < 3; ++i)
#pragma unroll
        for (int j = 0; j < 8; ++j) acc[i][j] = {0.f, 0.f, 0.f, 0.f};

#pragma unroll
    for (int s = 0; s < 6; ++s) {
        short8 af[3];
#pragma unroll
        for (int mt = 0; mt < 3; ++mt)
            af[mt] = *reinterpret_cast<const short8*>(
                A + (long)(wave * 48 + mt * 16 + l15) * K + s * 32 + g * 8);
        short8 bf[8];
#pragma unroll
        for (int nt = 0; nt < 8; ++nt)
            bf[nt] = *reinterpret_cast<const short8*>(
                &Bsv[nt * 16 + l15][s * 32 + g * 8]);
#pragma unroll
        for (int nt = 0; nt < 8; ++nt)
#pragma unroll
            for (int mt = 0; mt < 3; ++mt)
                acc[mt][nt] = __builtin_amdgcn_mfma_f32_16x16x32_bf16(
                    af[mt], bf[nt], acc[mt][nt], 0, 0, 0);
    }

    const long n0 = (long)r * 128;
#pragma unroll
    for (int mt = 0; mt < 3; ++mt) {
#pragma unroll
        for (int nt = 0; nt < 8; ++nt) {
            const int row = wave * 48 + mt * 16 + g * 4;
            const long col = n0 + nt * 16 + l15;
#pragma unroll
            for (int rr2 = 0; rr2 < 4; ++rr2)
                __builtin_nontemporal_store(acc[mt][nt][rr2],
                                            &C[(long)(row + rr2) * N + col]);
        }
    }
}

// ---------------------------------------------------------------------------
// Per (b,h): reduce partials, softmax(G/(nq*nk)*T), fold w_out:
// M[c, 48h+e] = sum_d w_out[c, 48h+d] * attn[d,e]
// ---------------------------------------------------------------------------
__global__ void __launch_bounds__(256) attn_m_kernel(
    const float* __restrict__ Gpart,        // [B,4,16,2304]
    const float* __restrict__ nqPart,       // [B,192,16]
    const float* __restrict__ nkPart,       // [B,192,16]
    const float* __restrict__ w_out,        // [192,192] fp32
    const float* __restrict__ temperature,  // [4]
    unsigned short* __restrict__ Mmat)      // [B,192,192] bf16
{
    const int blk = blockIdx.x;
    const int b = blk >> 2, h = blk & 3;
    const int tid = threadIdx.x;
    __shared__ float G[2304];
    __shared__ float At[2304];
    __shared__ float nqv[48], nkv[48];

    const long base = ((long)(b * 4 + h)) * 16;
    for (int i = tid; i < 2304; i += 256) {
        float s = 0.f;
        for (int c = 0; c < 16; ++c) s += Gpart[(base + c) * 2304 + i];
        G[i] = s;
    }
    if (tid < 96) {
        const int isK = tid >= 48;
        const int d = tid - 48 * isK;
        const float* p = (isK ? nkPart : nqPart) + ((long)b * 192 + h * 48 + d) * 16;
        float s = 0.f;
        for (int i = 0; i < 16; ++i) s += p[i];
        const float nrm = fmaxf(sqrtf(s), 1e-12f);
        if (isK) nkv[d] = nrm; else nqv[d] = nrm;
    }
    __syncthreads();

    const float T = temperature[h];
    if (tid < 48) {
        const int d = tid;
        const float scale = T / nqv[d];
        float m = -1e30f;
        for (int e = 0; e < 48; ++e) {
            const float sv = G[d * 48 + e] * scale / nkv[e];
            At[d * 48 + e] = sv;
            m = fmaxf(m, sv);
        }
        float sum = 0.f;
        for (int e = 0; e < 48; ++e) {
            const float ex = expf(At[d * 48 + e] - m);
            At[d * 48 + e] = ex;
            sum += ex;
        }
        const float inv = 1.f / sum;
        for (int e = 0; e < 48; ++e) At[d * 48 + e] *= inv;
    }
    __syncthreads();

    for (int i = tid; i < 192 * 48; i += 256) {
        const int c = i / 48, e = i - (i / 48) * 48;
        const float* wrow = w_out + (long)c * 192 + h * 48;
        float s = 0.f;
        for (int d = 0; d < 48; ++d) s += wrow[d] * At[d * 48 + e];
        Mmat[((long)b * 192 + c) * 192 + h * 48 + e] = f2b(s);
    }
}

// ---------------------------------------------------------------------------
extern "C" void kernel_launch(void* const* d_in, const int* in_sizes, int n_in,
                              void* d_out, int out_size, void* d_ws, size_t ws_size,
                              hipStream_t stream)
{
    const float* f_opt  = (const float*)d_in[0];
    const float* f_sar  = (const float*)d_in[1];
    const float* w_q    = (const float*)d_in[2];
    const float* w_qdw  = (const float*)d_in[3];
    const float* w_kv   = (const float*)d_in[4];
    const float* w_kvdw = (const float*)d_in[5];
    const float* w_out  = (const float*)d_in[6];
    const float* temper = (const float*)d_in[7];
    float* out = (float*)d_out;

    const long N = 16384;
    char* ws = (char*)d_ws;
    size_t off = 0;
    auto alloc = [&](size_t bytes) -> void* {
        void* p = ws + off;
        off = (off + bytes + 255) & ~(size_t)255;
        return p;
    };

    unsigned short* wq_b  = (unsigned short*)alloc((size_t)192 * 192 * 2);
    unsigned short* wkv_b = (unsigned short*)alloc((size_t)384 * 192 * 2);
    unsigned short* Mmat  = (unsigned short*)alloc((size_t)8 * 192 * 192 * 2);
    float* Gpart  = (float*)alloc((size_t)8 * 4 * 16 * 2304 * 4);
    float* nqPart = (float*)alloc((size_t)8 * 192 * 16 * 4);
    float* nkPart = (float*)alloc((size_t)8 * 192 * 16 * 4);
    unsigned short* q0   = (unsigned short*)alloc((size_t)8 * 192 * N * 2);
    unsigned short* kv0  = (unsigned short*)alloc((size_t)8 * 384 * N * 2);

    cvt_weights<<<dim3((192*192 + 384*192 + 255) / 256), 256, 0, stream>>>(
        w_q, w_kv, wq_b, wkv_b);

    // q + k projections (dwgram's inputs)
    proj_qk<<<dim3(128, 2, 8), 256, 0, stream>>>(
        wq_b, wkv_b, f_opt, f_sar, q0, kv0);

    // dwgram (x<64) runs concurrently with the independent v projection (x>=64)
    dwgram_projv<<<dim3(192, 1, 8), 256, 0, stream>>>(
        q0, kv0, wkv_b, f_sar, w_qdw, w_kvdw,
        Gpart, nqPart, nkPart, kv0);

    attn_m_kernel<<<dim3(32), 256, 0, stream>>>(
        Gpart, nqPart, nkPart, w_out, temper, Mmat);

    final_gemm_fused<<<dim3(128, 1, 8), 256, 0, stream>>>(
        Mmat, kv0, w_kvdw, out);
}

// Round 15
// 260.319 us; speedup vs baseline: 1.2110x; 1.2110x over previous
//
#include <hip/hip_runtime.h>
#include <hip/hip_bf16.h>

// CrossModalMDTA on gfx950 — round 15.
// r13 structure + fp8(e4m3, HW cvt, x64 scale) storage for q0/k0 — the
// gram/norm path is exactly scale-invariant, so the x64 scale never needs
// undoing and fp8's 3% element error becomes ~0.02% on logits. v stays bf16.
// Cuts ~100 MB HBM traffic (proj writes + dwgram reads).

typedef __attribute__((ext_vector_type(8))) short short8;   // 8 x bf16
typedef __attribute__((ext_vector_type(4))) float f32x4;    // MFMA accum
typedef __attribute__((ext_vector_type(2))) float f32x2;

static __device__ __forceinline__ float b2f(unsigned short u) {
    return __uint_as_float(((unsigned)u) << 16);
}
static __device__ __forceinline__ unsigned short f2b(float f) {
    unsigned u = __float_as_uint(f);
    u += 0x7FFFu + ((u >> 16) & 1u);          // RNE
    return (unsigned short)(u >> 16);
}
static __device__ __forceinline__ unsigned short f2bh(float f) {
    union { __hip_bfloat16 h; unsigned short u; } cv;
    cv.h = __float2bfloat16(f);
    return cv.u;
}

// one launch converts both weight tensors
__global__ void cvt_weights(const float* __restrict__ w_q,
                            const float* __restrict__ w_kv,
                            unsigned short* __restrict__ wq_b,
                            unsigned short* __restrict__ wkv_b) {
    const int i = blockIdx.x * 256 + threadIdx.x;
    if (i < 192 * 192) wq_b[i] = f2b(w_q[i]);
    const int j = i - 192 * 192;
    if (j >= 0 && j < 384 * 192) wkv_b[j] = f2b(w_kv[j]);
}

// ---------------------------------------------------------------------------
// GEMM body (r8-proven): C[m,n] = sum_k A[m,k]*B[k,n], K=192, fp32 B,
// tile 192m x 128n, 4 waves, split-K=64 double-buffered.
// FP8OUT: scale x64, encode e4m3 via v_cvt_pk_fp8_f32, byte stores.
// ---------------------------------------------------------------------------
template<bool FP8OUT>
static __device__ __forceinline__ void gemm_body(
    const unsigned short* __restrict__ A,   // bf16 [192 x 192]
    const float* __restrict__ B,            // [192 x N] fp32
    void* __restrict__ Cout)                // fp8 bytes or bf16 ushorts
{
    constexpr long N = 16384;
    constexpr int K = 192;
    const int tid  = threadIdx.x;
    const int wave = tid >> 6;
    const int lane = tid & 63;
    const int l15  = lane & 15;
    const int g    = lane >> 4;
    const long n0  = (long)blockIdx.x * 128;

    __shared__ unsigned short Bs[2][128][72];   // 36.9 KB

    const int nc = tid & 127;
    const int kb = tid >> 7;

    float fv[4][8];

    auto load_regs = [&](int s) {
#pragma unroll
        for (int i = 0; i < 4; ++i) {
            const int kc = kb + 2 * i;
            const float* bp = B + (long)(s * 64 + kc * 8) * N + n0 + nc;
#pragma unroll
            for (int j = 0; j < 8; ++j) fv[i][j] = bp[j * N];
        }
    };
    auto write_lds = [&](int buf) {
#pragma unroll
        for (int i = 0; i < 4; ++i) {
            const int kc = kb + 2 * i;
            unsigned w[4];
#pragma unroll
            for (int t = 0; t < 4; ++t)
                w[t] = (unsigned)f2bh(fv[i][2*t]) | ((unsigned)f2bh(fv[i][2*t+1]) << 16);
            uint4 pk = {w[0], w[1], w[2], w[3]};
            *reinterpret_cast<uint4*>(&Bs[buf][nc][kc * 8]) = pk;
        }
    };

    f32x4 acc[3][8];
#pragma unroll
    for (int i = 0; i < 3; ++i)
#pragma unroll
        for (int j = 0; j < 8; ++j) acc[i][j] = {0.f, 0.f, 0.f, 0.f};

    load_regs(0);
    write_lds(0);
    __syncthreads();

#pragma unroll
    for (int s = 0; s < 3; ++s) {
        const int buf = s & 1;
        if (s < 2) load_regs(s + 1);
#pragma unroll
        for (int s32 = 0; s32 < 2; ++s32) {
            short8 af[3];
#pragma unroll
            for (int mt = 0; mt < 3; ++mt)
                af[mt] = *reinterpret_cast<const short8*>(
                    A + (long)(wave * 48 + mt * 16 + l15) * K + s * 64 + s32 * 32 + g * 8);
            short8 bf[8];
#pragma unroll
            for (int nt = 0; nt < 8; ++nt)
                bf[nt] = *reinterpret_cast<const short8*>(
                    &Bs[buf][nt * 16 + l15][s32 * 32 + g * 8]);
#pragma unroll
            for (int nt = 0; nt < 8; ++nt)
#pragma unroll
                for (int mt = 0; mt < 3; ++mt)
                    acc[mt][nt] = __builtin_amdgcn_mfma_f32_16x16x32_bf16(
                        af[mt], bf[nt], acc[mt][nt], 0, 0, 0);
        }
        if (s < 2) {
            write_lds(buf ^ 1);
            __syncthreads();
        }
    }

#pragma unroll
    for (int mt = 0; mt < 3; ++mt) {
#pragma unroll
        for (int nt = 0; nt < 8; ++nt) {
            const int row = wave * 48 + mt * 16 + g * 4;
            const long col = n0 + nt * 16 + l15;
            if constexpr (FP8OUT) {
                unsigned char* Cb = (unsigned char*)Cout;
                const int p01 = __builtin_amdgcn_cvt_pk_fp8_f32(
                    acc[mt][nt][0] * 64.f, acc[mt][nt][1] * 64.f, 0, false);
                const int p23 = __builtin_amdgcn_cvt_pk_fp8_f32(
                    acc[mt][nt][2] * 64.f, acc[mt][nt][3] * 64.f, 0, false);
                Cb[(long)(row + 0) * N + col] = (unsigned char)(p01 & 0xFF);
                Cb[(long)(row + 1) * N + col] = (unsigned char)((p01 >> 8) & 0xFF);
                Cb[(long)(row + 2) * N + col] = (unsigned char)(p23 & 0xFF);
                Cb[(long)(row + 3) * N + col] = (unsigned char)((p23 >> 8) & 0xFF);
            } else {
                unsigned short* Cs = (unsigned short*)Cout;
#pragma unroll
                for (int r = 0; r < 4; ++r)
                    Cs[(long)(row + r) * N + col] = f2b(acc[mt][nt][r]);
            }
        }
    }
}

// fused q + k + v projection: y==0 -> q0(fp8) ; y==1 -> k0(fp8) ; y==2 -> v0(bf16)
__global__ void __launch_bounds__(256) proj_gemm(
    const unsigned short* __restrict__ wq_b,
    const unsigned short* __restrict__ wkv_b,
    const float* __restrict__ f_opt,
    const float* __restrict__ f_sar,
    unsigned char* __restrict__ q0,          // [B][192][N] fp8 (x64)
    unsigned char* __restrict__ k0,          // [B][192][N] fp8 (x64)
    unsigned short* __restrict__ v0)         // [B][192][N] bf16
{
    constexpr long N = 16384;
    const int b = blockIdx.z;
    const int y = blockIdx.y;
    if (y == 0) {
        gemm_body<true>(wq_b, f_opt + (long)b * 192 * N, q0 + (long)b * 192 * N);
    } else if (y == 1) {
        gemm_body<true>(wkv_b, f_sar + (long)b * 192 * N, k0 + (long)b * 192 * N);
    } else {
        gemm_body<false>(wkv_b + (size_t)192 * 192,
                         f_sar + (long)b * 192 * N, v0 + (long)b * 192 * N);
    }
}

// ---------------------------------------------------------------------------
// dwgram: fused depthwise-3x3 (q,k from fp8 x64 storage) + gram partial.
// All values carry the x64 scale through dw, gram and norms — it cancels in
// softmax(G/(||q|| ||k||)) exactly.
// ---------------------------------------------------------------------------
__global__ void __launch_bounds__(256, 2) dwgram(
    const unsigned char* __restrict__ q0,    // [B][192][N] fp8
    const unsigned char* __restrict__ k0,    // [B][192][N] fp8
    const float* __restrict__ w_qdw,         // [192][9]
    const float* __restrict__ w_kvdw,        // [384][9]
    float* __restrict__ Gpart,               // [B][4][16][2304]
    float* __restrict__ nqPart,              // [B][192][16]
    float* __restrict__ nkPart)              // [B][192][16]
{
    constexpr long NP = 16384;
    const int chunk = blockIdx.x;            // 0..15 (8 rows each)
    const int h     = blockIdx.y;
    const int b     = blockIdx.z;

    const int tid  = threadIdx.x;
    const int wave = tid >> 6;               // 0..3 = k-step
    const int lane = tid & 63;
    const int l15  = lane & 15;
    const int g    = lane >> 4;

    const int w0     = (tid & 15) * 8;
    const int chBase = tid >> 4;             // 0..15

    __shared__ __align__(16) unsigned short smem[2][96][136];  // 51 KB dbuf

    const unsigned char* srcs[6];
    float wt[6][9];
    float nacc[6];
#pragma unroll
    for (int tt = 0; tt < 6; ++tt) {
        const int ch_loc = tt * 16 + chBase;
        const float* wp;
        if (ch_loc < 48) {
            const int c = 48 * h + ch_loc;
            srcs[tt] = q0 + ((long)b * 192 + c) * NP;
            wp = w_qdw + c * 9;
        } else {
            const int c = 48 * h + ch_loc - 48;
            srcs[tt] = k0 + ((long)b * 192 + c) * NP;
            wp = w_kvdw + c * 9;
        }
#pragma unroll
        for (int i = 0; i < 9; ++i) wt[tt][i] = wp[i];
        nacc[tt] = 0.f;
    }

    f32x4 acc[3][3];
#pragma unroll
    for (int i = 0; i < 3; ++i)
#pragma unroll
        for (int j = 0; j < 3; ++j) acc[i][j] = {0.f, 0.f, 0.f, 0.f};

    auto dw_step = [&](int s, int buf) {
        const int r = chunk * 8 + s;
#pragma unroll
        for (int tt = 0; tt < 6; ++tt) {
            float a8[8] = {0, 0, 0, 0, 0, 0, 0, 0};
#pragma unroll
            for (int dy = 0; dy < 3; ++dy) {
                const int hy = r + dy - 1;
                if (hy < 0 || hy > 127) continue;
                const unsigned char* row = srcs[tt] + hy * 128 + w0;
                const uint2 u = *reinterpret_cast<const uint2*>(row);
                float rr[10];
                const f32x2 d0 = __builtin_amdgcn_cvt_pk_f32_fp8(u.x, false);
                const f32x2 d1 = __builtin_amdgcn_cvt_pk_f32_fp8(u.x, true);
                const f32x2 d2 = __builtin_amdgcn_cvt_pk_f32_fp8(u.y, false);
                const f32x2 d3 = __builtin_amdgcn_cvt_pk_f32_fp8(u.y, true);
                rr[1] = d0.x; rr[2] = d0.y; rr[3] = d1.x; rr[4] = d1.y;
                rr[5] = d2.x; rr[6] = d2.y; rr[7] = d3.x; rr[8] = d3.y;
                const float left  = __shfl_up(rr[8], 1);
                const float right = __shfl_down(rr[1], 1);
                rr[0] = (l15 > 0)  ? left  : 0.f;
                rr[9] = (l15 < 15) ? right : 0.f;
#pragma unroll
                for (int j = 0; j < 8; ++j)
                    a8[j] += wt[tt][dy*3+0]*rr[j] + wt[tt][dy*3+1]*rr[j+1]
                           + wt[tt][dy*3+2]*rr[j+2];
            }
            float ss = 0.f;
#pragma unroll
            for (int j = 0; j < 8; ++j) ss += a8[j] * a8[j];
            nacc[tt] += ss;
            unsigned u[4];
#pragma unroll
            for (int t2 = 0; t2 < 4; ++t2)
                u[t2] = (unsigned)f2bh(a8[2*t2]) | ((unsigned)f2bh(a8[2*t2+1]) << 16);
            uint4 pk = {u[0], u[1], u[2], u[3]};
            *reinterpret_cast<uint4*>(&smem[buf][tt * 16 + chBase][w0]) = pk;
        }
    };

    auto mma_step = [&](int buf) {
        short8 af[3], bf[3];
#pragma unroll
        for (int mt = 0; mt < 3; ++mt)
            af[mt] = *reinterpret_cast<const short8*>(
                &smem[buf][mt * 16 + l15][wave * 32 + g * 8]);
#pragma unroll
        for (int nt = 0; nt < 3; ++nt)
            bf[nt] = *reinterpret_cast<const short8*>(
                &smem[buf][48 + nt * 16 + l15][wave * 32 + g * 8]);
#pragma unroll
        for (int mt = 0; mt < 3; ++mt)
#pragma unroll
            for (int nt = 0; nt < 3; ++nt)
                acc[mt][nt] = __builtin_amdgcn_mfma_f32_16x16x32_bf16(
                    af[mt], bf[nt], acc[mt][nt], 0, 0, 0);
    };

    dw_step(0, 0);
    __syncthreads();
#pragma unroll 1
    for (int s = 0; s < 8; ++s) {
        const int buf = s & 1;
        if (s < 7) dw_step(s + 1, buf ^ 1);
        mma_step(buf);
        __syncthreads();
    }

    float* Gt = reinterpret_cast<float*>(&smem[0][0][0]);
#pragma unroll
    for (int mt = 0; mt < 3; ++mt)
#pragma unroll
        for (int nt = 0; nt < 3; ++nt)
#pragma unroll
            for (int r = 0; r < 4; ++r)
                Gt[wave * 2304 + (mt*16 + g*4 + r) * 48 + nt*16 + l15] = acc[mt][nt][r];
    __syncthreads();

    float* gout = Gpart + (((long)(b * 4 + h)) * 16 + chunk) * 2304;
    for (int i = tid; i < 2304; i += 256)
        gout[i] = Gt[i] + Gt[2304 + i] + Gt[4608 + i] + Gt[6912 + i];

#pragma unroll
    for (int tt = 0; tt < 6; ++tt) {
        float ssv = nacc[tt];
        ssv += __shfl_xor(ssv, 1);
        ssv += __shfl_xor(ssv, 2);
        ssv += __shfl_xor(ssv, 4);
        ssv += __shfl_xor(ssv, 8);
        if ((tid & 15) == 0) {
            const int ch_loc = tt * 16 + chBase;
            if (ch_loc < 48)
                nqPart[((long)b * 192 + 48 * h + ch_loc) * 16 + chunk] = ssv;
            else
                nkPart[((long)b * 192 + 48 * h + ch_loc - 48) * 16 + chunk] = ssv;
        }
    }
}

// ---------------------------------------------------------------------------
// final GEMM fused with dw3x3(v): block = (image row r, batch b). (round 13)
// v0 is now its own bf16 buffer [B][192][N].
// ---------------------------------------------------------------------------
__global__ void __launch_bounds__(256) final_gemm_fused(
    const unsigned short* __restrict__ Mmat,   // [B,192,192] bf16
    const unsigned short* __restrict__ v0all,  // [B,192,N] bf16 (pre-dw v)
    const float* __restrict__ w_kvdw,          // [384][9]
    float* __restrict__ out)                   // [B,192,N] fp32
{
    constexpr long N = 16384;
    constexpr int K = 192;
    const int r = blockIdx.x;                  // image row 0..127
    const int b = blockIdx.z;
    const unsigned short* v0 = v0all + (long)b * 192 * N;
    const unsigned short* A  = Mmat + (long)b * 192 * 192;
    float* C = out + (long)b * 192 * N;

    const int tid  = threadIdx.x;
    const int wave = tid >> 6;
    const int lane = tid & 63;
    const int l15  = lane & 15;
    const int g    = lane >> 4;

    __shared__ __align__(16) unsigned short Bsv[128][200];   // [px][ch] 51.2 KB

    const int l16   = tid & 15;
    const int pBase = l16 * 8;
    const int cp    = tid >> 4;                // 0..15

#pragma unroll
    for (int t6 = 0; t6 < 6; ++t6) {
        const int c0 = t6 * 32 + cp * 2;
        float a8[2][8];
#pragma unroll
        for (int e = 0; e < 2; ++e)
#pragma unroll
            for (int j = 0; j < 8; ++j) a8[e][j] = 0.f;

#pragma unroll
        for (int e = 0; e < 2; ++e) {
            const int c = c0 + e;
            const float* wp = w_kvdw + (192 + c) * 9;
            float wt[9];
#pragma unroll
            for (int i = 0; i < 9; ++i) wt[i] = wp[i];
            const unsigned short* src = v0 + (long)c * N;
#pragma unroll
            for (int dy = 0; dy < 3; ++dy) {
                const int hy = r + dy - 1;
                if (hy < 0 || hy > 127) continue;
                const unsigned short* row = src + hy * 128 + pBase;
                float rr[10];
                const short8 v = *reinterpret_cast<const short8*>(row);
#pragma unroll
                for (int i = 0; i < 8; ++i) rr[i + 1] = b2f((unsigned short)v[i]);
                const float left  = __shfl_up(rr[8], 1);
                const float right = __shfl_down(rr[1], 1);
                rr[0] = (l16 > 0)  ? left  : 0.f;
                rr[9] = (l16 < 15) ? right : 0.f;
#pragma unroll
                for (int j = 0; j < 8; ++j)
                    a8[e][j] += wt[dy*3+0]*rr[j] + wt[dy*3+1]*rr[j+1]
                              + wt[dy*3+2]*rr[j+2];
            }
        }
#pragma unroll
        for (int j = 0; j < 8; ++j) {
            const unsigned u = (unsigned)f2bh(a8[0][j])
                             | ((unsigned)f2bh(a8[1][j]) << 16);
            *reinterpret_cast<unsigned*>(&Bsv[pBase + j][c0]) = u;
        }
    }
    __syncthreads();

    f32x4 acc[3][8];
#pragma unroll
    for (int i = 0; i < 3; ++i)
#pragma unroll
        for (int j = 0; j < 8; ++j) acc[i][j] = {0.f, 0.f, 0.f, 0.f};

#pragma unroll
    for (int s = 0; s < 6; ++s) {
        short8 af[3];
#pragma unroll
        for (int mt = 0; mt < 3; ++mt)
            af[mt] = *reinterpret_cast<const short8*>(
                A + (long)(wave * 48 + mt * 16 + l15) * K + s * 32 + g * 8);
        short8 bf[8];
#pragma unroll
        for (int nt = 0; nt < 8; ++nt)
            bf[nt] = *reinterpret_cast<const short8*>(
                &Bsv[nt * 16 + l15][s * 32 + g * 8]);
#pragma unroll
        for (int nt = 0; nt < 8; ++nt)
#pragma unroll
            for (int mt = 0; mt < 3; ++mt)
                acc[mt][nt] = __builtin_amdgcn_mfma_f32_16x16x32_bf16(
                    af[mt], bf[nt], acc[mt][nt], 0, 0, 0);
    }

    const long n0 = (long)r * 128;
#pragma unroll
    for (int mt = 0; mt < 3; ++mt) {
#pragma unroll
        for (int nt = 0; nt < 8; ++nt) {
            const int row = wave * 48 + mt * 16 + g * 4;
            const long col = n0 + nt * 16 + l15;
#pragma unroll
            for (int rr2 = 0; rr2 < 4; ++rr2)
                __builtin_nontemporal_store(acc[mt][nt][rr2],
                                            &C[(long)(row + rr2) * N + col]);
        }
    }
}

// ---------------------------------------------------------------------------
// Per (b,h): reduce partials, softmax(G/(nq*nk)*T), fold w_out:
// M[c, 48h+e] = sum_d w_out[c, 48h+d] * attn[d,e]
// (The x64 fp8 scale cancels exactly: G ~ s^2, nq*nk ~ s^2.)
// ---------------------------------------------------------------------------
__global__ void __launch_bounds__(256) attn_m_kernel(
    const float* __restrict__ Gpart,        // [B,4,16,2304]
    const float* __restrict__ nqPart,       // [B,192,16]
    const float* __restrict__ nkPart,       // [B,192,16]
    const float* __restrict__ w_out,        // [192,192] fp32
    const float* __restrict__ temperature,  // [4]
    unsigned short* __restrict__ Mmat)      // [B,192,192] bf16
{
    const int blk = blockIdx.x;
    const int b = blk >> 2, h = blk & 3;
    const int tid = threadIdx.x;
    __shared__ float G[2304];
    __shared__ float At[2304];
    __shared__ float nqv[48], nkv[48];

    const long base = ((long)(b * 4 + h)) * 16;
    for (int i = tid; i < 2304; i += 256) {
        float s = 0.f;
        for (int c = 0; c < 16; ++c) s += Gpart[(base + c) * 2304 + i];
        G[i] = s;
    }
    if (tid < 96) {
        const int isK = tid >= 48;
        const int d = tid - 48 * isK;
        const float* p = (isK ? nkPart : nqPart) + ((long)b * 192 + h * 48 + d) * 16;
        float s = 0.f;
        for (int i = 0; i < 16; ++i) s += p[i];
        const float nrm = fmaxf(sqrtf(s), 1e-12f);
        if (isK) nkv[d] = nrm; else nqv[d] = nrm;
    }
    __syncthreads();

    const float T = temperature[h];
    if (tid < 48) {
        const int d = tid;
        const float scale = T / nqv[d];
        float m = -1e30f;
        for (int e = 0; e < 48; ++e) {
            const float sv = G[d * 48 + e] * scale / nkv[e];
            At[d * 48 + e] = sv;
            m = fmaxf(m, sv);
        }
        float sum = 0.f;
        for (int e = 0; e < 48; ++e) {
            const float ex = expf(At[d * 48 + e] - m);
            At[d * 48 + e] = ex;
            sum += ex;
        }
        const float inv = 1.f / sum;
        for (int e = 0; e < 48; ++e) At[d * 48 + e] *= inv;
    }
    __syncthreads();

    for (int i = tid; i < 192 * 48; i += 256) {
        const int c = i / 48, e = i - (i / 48) * 48;
        const float* wrow = w_out + (long)c * 192 + h * 48;
        float s = 0.f;
        for (int d = 0; d < 48; ++d) s += wrow[d] * At[d * 48 + e];
        Mmat[((long)b * 192 + c) * 192 + h * 48 + e] = f2b(s);
    }
}

// ---------------------------------------------------------------------------
extern "C" void kernel_launch(void* const* d_in, const int* in_sizes, int n_in,
                              void* d_out, int out_size, void* d_ws, size_t ws_size,
                              hipStream_t stream)
{
    const float* f_opt  = (const float*)d_in[0];
    const float* f_sar  = (const float*)d_in[1];
    const float* w_q    = (const float*)d_in[2];
    const float* w_qdw  = (const float*)d_in[3];
    const float* w_kv   = (const float*)d_in[4];
    const float* w_kvdw = (const float*)d_in[5];
    const float* w_out  = (const float*)d_in[6];
    const float* temper = (const float*)d_in[7];
    float* out = (float*)d_out;

    const long N = 16384;
    char* ws = (char*)d_ws;
    size_t off = 0;
    auto alloc = [&](size_t bytes) -> void* {
        void* p = ws + off;
        off = (off + bytes + 255) & ~(size_t)255;
        return p;
    };

    unsigned short* wq_b  = (unsigned short*)alloc((size_t)192 * 192 * 2);
    unsigned short* wkv_b = (unsigned short*)alloc((size_t)384 * 192 * 2);
    unsigned short* Mmat  = (unsigned short*)alloc((size_t)8 * 192 * 192 * 2);
    float* Gpart  = (float*)alloc((size_t)8 * 4 * 16 * 2304 * 4);
    float* nqPart = (float*)alloc((size_t)8 * 192 * 16 * 4);
    float* nkPart = (float*)alloc((size_t)8 * 192 * 16 * 4);
    unsigned char*  q0 = (unsigned char*)alloc((size_t)8 * 192 * N);      // fp8
    unsigned char*  k0 = (unsigned char*)alloc((size_t)8 * 192 * N);      // fp8
    unsigned short* v0 = (unsigned short*)alloc((size_t)8 * 192 * N * 2); // bf16

    cvt_weights<<<dim3((192*192 + 384*192 + 255) / 256), 256, 0, stream>>>(
        w_q, w_kv, wq_b, wkv_b);

    proj_gemm<<<dim3(128, 3, 8), 256, 0, stream>>>(
        wq_b, wkv_b, f_opt, f_sar, q0, k0, v0);

    dwgram<<<dim3(16, 4, 8), 256, 0, stream>>>(
        q0, k0, w_qdw, w_kvdw, Gpart, nqPart, nkPart);

    attn_m_kernel<<<dim3(32), 256, 0, stream>>>(
        Gpart, nqPart, nkPart, w_out, temper, Mmat);

    final_gemm_fused<<<dim3(128, 1, 8), 256, 0, stream>>>(
        Mmat, v0, w_kvdw, out);
}